// Round 7
// baseline (213.482 us; speedup 1.0000x reference)
//
#include <hip/hip_runtime.h>
#include <math.h>

#define GDIM 128
#define CDIM 32
#define EPSV 1e-8f
#define INV_SIGMA 10.0f
#define PAD 4   // row stride 132 floats -> near-conflict-free strided reads

// ---- round-4 structure (best measured: ~62 us) ----
__global__ __launch_bounds__(256, 8) void nc_kernel(
    const float* __restrict__ x, const float* __restrict__ v,
    const int*   __restrict__ k, const float* __restrict__ X,
    float* __restrict__ out)
{
    const int i = blockIdx.x;
    const int t = threadIdx.x;

    __shared__ float sdel[CDIM][GDIM + PAD];  // 32 x 132 x 4B = 16.9 KB
    __shared__ float sv[GDIM];
    __shared__ float stv[CDIM];
    __shared__ float s_vnorm;
    __shared__ float s_mean;

    float va = 0.f, vb = 0.f;
    if (t < 64) {
        va = v[(size_t)i * GDIM + t];
        vb = v[(size_t)i * GDIM + t + 64];
    }

    const int lane4 = (t & 31) * 4;
    const int cbase = t >> 5;
    int k0 = k[(size_t)i * CDIM + cbase];
    int k1 = k[(size_t)i * CDIM + cbase + 8];
    int k2 = k[(size_t)i * CDIM + cbase + 16];
    int k3 = k[(size_t)i * CDIM + cbase + 24];
    const float4 xv = *reinterpret_cast<const float4*>(&x[(size_t)i * GDIM + lane4]);
    const float4 X0 = *reinterpret_cast<const float4*>(&X[(size_t)k0 * GDIM + lane4]);
    const float4 X1 = *reinterpret_cast<const float4*>(&X[(size_t)k1 * GDIM + lane4]);
    const float4 X2 = *reinterpret_cast<const float4*>(&X[(size_t)k2 * GDIM + lane4]);
    const float4 X3 = *reinterpret_cast<const float4*>(&X[(size_t)k3 * GDIM + lane4]);

    if (t < 64) {
        sv[t] = va; sv[t + 64] = vb;
        float vn = va * va + vb * vb;
        #pragma unroll
        for (int off = 32; off; off >>= 1) vn += __shfl_xor(vn, off);
        if (t == 0) s_vnorm = sqrtf(vn);
    }

    {
        float4 d;
        d.x = X0.x - xv.x; d.y = X0.y - xv.y; d.z = X0.z - xv.z; d.w = X0.w - xv.w;
        *reinterpret_cast<float4*>(&sdel[cbase][lane4]) = d;
        d.x = X1.x - xv.x; d.y = X1.y - xv.y; d.z = X1.z - xv.z; d.w = X1.w - xv.w;
        *reinterpret_cast<float4*>(&sdel[cbase + 8][lane4]) = d;
        d.x = X2.x - xv.x; d.y = X2.y - xv.y; d.z = X2.z - xv.z; d.w = X2.w - xv.w;
        *reinterpret_cast<float4*>(&sdel[cbase + 16][lane4]) = d;
        d.x = X3.x - xv.x; d.y = X3.y - xv.y; d.z = X3.z - xv.z; d.w = X3.w - xv.w;
        *reinterpret_cast<float4*>(&sdel[cbase + 24][lane4]) = d;
    }
    __syncthreads();  // B1

    {
        const int c = t >> 3;
        const int l = t & 7;
        float num = 0.f, ss = 0.f;
        #pragma unroll
        for (int j = 0; j < 16; ++j) {
            const int g = l + 8 * j;
            const float d = sdel[c][g];
            num = fmaf(sv[g], d, num);
            ss  = fmaf(d, d, ss);
        }
        #pragma unroll
        for (int off = 4; off; off >>= 1) {
            num += __shfl_xor(num, off);
            ss  += __shfl_xor(ss, off);
        }
        if (l == 0) {
            const float dn = sqrtf(ss);
            const float cs = num / fmaxf(s_vnorm * dn, EPSV);
            stv[c] = expm1f(cs * INV_SIGMA);
        }
    }
    __syncthreads();  // B2

    if (t < CDIM) {
        const float tv = stv[t];
        float sa = fabsf(tv), st = tv;
        #pragma unroll
        for (int off = 16; off; off >>= 1) {
            sa += __shfl_xor(sa, off);
            st += __shfl_xor(st, off);
        }
        stv[t] = tv / sa;
        if (t == 0) s_mean = (st / sa) * (1.0f / CDIM);
    }
    __syncthreads();  // B3

    if (t < GDIM) {
        const int g = t;
        float acc = 0.f, sd = 0.f;
        #pragma unroll
        for (int c = 0; c < CDIM; ++c) {
            const float d = sdel[c][g];
            acc = fmaf(d, stv[c], acc);
            sd += d;
        }
        out[(size_t)i * GDIM + g] = acc - s_mean * sd;
    }
}

// ---- comparator: pure gather, identical pattern, no LDS/barriers/compute ----
// Runs AFTER nc_kernel (so nc sees the standard cold state). Loads kept live
// via asm sink (no DCE, no stores besides none).
__global__ __launch_bounds__(256, 8) void gather_bench(
    const int* __restrict__ k, const float* __restrict__ X)
{
    const int i = blockIdx.x;
    const int t = threadIdx.x;
    const int lane4 = (t & 31) * 4;
    const int cbase = t >> 5;
    int k0 = k[(size_t)i * CDIM + cbase];
    int k1 = k[(size_t)i * CDIM + cbase + 8];
    int k2 = k[(size_t)i * CDIM + cbase + 16];
    int k3 = k[(size_t)i * CDIM + cbase + 24];
    const float4 X0 = *reinterpret_cast<const float4*>(&X[(size_t)k0 * GDIM + lane4]);
    const float4 X1 = *reinterpret_cast<const float4*>(&X[(size_t)k1 * GDIM + lane4]);
    const float4 X2 = *reinterpret_cast<const float4*>(&X[(size_t)k2 * GDIM + lane4]);
    const float4 X3 = *reinterpret_cast<const float4*>(&X[(size_t)k3 * GDIM + lane4]);
    float s = X0.x + X0.y + X0.z + X0.w + X1.x + X1.y + X1.z + X1.w
            + X2.x + X2.y + X2.z + X2.w + X3.x + X3.y + X3.z + X3.w;
    asm volatile("" :: "v"(s));  // keep loads live, no memory traffic
}

extern "C" void kernel_launch(void* const* d_in, const int* in_sizes, int n_in,
                              void* d_out, int out_size, void* d_ws, size_t ws_size,
                              hipStream_t stream) {
    const float* x = (const float*)d_in[0];
    const float* v = (const float*)d_in[1];
    const int*   k = (const int*)  d_in[2];
    const float* X = (const float*)d_in[3];
    float* out = (float*)d_out;
    const int n = in_sizes[0] / GDIM;  // 16384 rows
    nc_kernel<<<n, 256, 0, stream>>>(x, v, k, X, out);
    gather_bench<<<n, 256, 0, stream>>>(k, X);
}

// Round 8
// 188.096 us; speedup vs baseline: 1.1350x; 1.1350x over previous
//
#include <hip/hip_runtime.h>
#include <math.h>

#define GDIM 128
#define CDIM 32
#define EPSV 1e-8f
#define INV_SIGMA 10.0f

// One wave per row. No LDS, no barriers — pure gather + in-register butterfly
// reductions, structurally identical to the 35us pure-gather comparator (r7).
// Per iteration: half-wave h loads row k[2*it+h] (lane = 4 dims, coalesced
// 512B per half-wave), butterfly-reduce dot(v,d) and ||d||^2 within the half,
// then online-accumulate A[g] += tv*d[g], S[g] += d[g].
// out[g] = (A[g] - (st/32)*S[g]) / sa, with sa=Sum|tv|, st=Sum tv.
__global__ __launch_bounds__(256) void nc_kernel(
    const float* __restrict__ x, const float* __restrict__ v,
    const int*   __restrict__ k, const float* __restrict__ X,
    float* __restrict__ out)
{
    const int t    = threadIdx.x;
    const int wave = t >> 6;           // 4 independent waves (rows) per block
    const int lane = t & 63;
    const int m    = lane & 31;        // dim-chunk index: dims m*4 .. m*4+3
    const int h    = lane >> 5;        // row-parity half
    const long i   = (long)blockIdx.x * 4 + wave;

    // per-lane x, v chunks (coalesced 512B per half-wave)
    const float4 xv = *reinterpret_cast<const float4*>(&x[i * GDIM + m * 4]);
    const float4 vv = *reinterpret_cast<const float4*>(&v[i * GDIM + m * 4]);

    // ||v||^2: lanes 0-31 cover all 128 dims -> butterfly within half
    float vn = vv.x * vv.x + vv.y * vv.y + vv.z * vv.z + vv.w * vv.w;
    #pragma unroll
    for (int off = 16; off; off >>= 1) vn += __shfl_xor(vn, off);
    const float vnorm = sqrtf(vn);

    // lane m holds k[i][m] (lanes 32-63 duplicate; readlane below)
    const int kk = k[i * CDIM + m];

    float4 A = make_float4(0.f, 0.f, 0.f, 0.f);
    float4 S = make_float4(0.f, 0.f, 0.f, 0.f);
    float  sa = 0.f, st = 0.f;

    #pragma unroll
    for (int it = 0; it < 16; ++it) {
        // row index for my half: k[2*it + h] via two uniform readlanes + select
        const int ke = __shfl(kk, 2 * it);
        const int ko = __shfl(kk, 2 * it + 1);
        const int kc = h ? ko : ke;

        const float4 Xr = *reinterpret_cast<const float4*>(
            &X[(size_t)kc * GDIM + m * 4]);
        float4 d;
        d.x = Xr.x - xv.x; d.y = Xr.y - xv.y;
        d.z = Xr.z - xv.z; d.w = Xr.w - xv.w;

        float num = vv.x * d.x + vv.y * d.y + vv.z * d.z + vv.w * d.w;
        float ss  = d.x * d.x + d.y * d.y + d.z * d.z + d.w * d.w;
        #pragma unroll
        for (int off = 16; off; off >>= 1) {
            num += __shfl_xor(num, off);
            ss  += __shfl_xor(ss, off);
        }

        const float cs = num / fmaxf(vnorm * sqrtf(ss), EPSV);
        const float tv = expm1f(cs * INV_SIGMA);
        sa += fabsf(tv);
        st += tv;

        A.x = fmaf(tv, d.x, A.x); A.y = fmaf(tv, d.y, A.y);
        A.z = fmaf(tv, d.z, A.z); A.w = fmaf(tv, d.w, A.w);
        S.x += d.x; S.y += d.y; S.z += d.z; S.w += d.w;
    }

    // combine row-parity halves (each lane saw 16 of the 32 neighbors)
    sa += __shfl_xor(sa, 32);
    st += __shfl_xor(st, 32);
    A.x += __shfl_xor(A.x, 32); A.y += __shfl_xor(A.y, 32);
    A.z += __shfl_xor(A.z, 32); A.w += __shfl_xor(A.w, 32);
    S.x += __shfl_xor(S.x, 32); S.y += __shfl_xor(S.y, 32);
    S.z += __shfl_xor(S.z, 32); S.w += __shfl_xor(S.w, 32);

    if (h == 0) {
        const float scale = 1.0f / sa;
        const float mst   = st * (1.0f / CDIM);
        float4 o;
        o.x = (A.x - mst * S.x) * scale;
        o.y = (A.y - mst * S.y) * scale;
        o.z = (A.z - mst * S.z) * scale;
        o.w = (A.w - mst * S.w) * scale;
        *reinterpret_cast<float4*>(&out[i * GDIM + m * 4]) = o;  // 512B coalesced
    }
}

extern "C" void kernel_launch(void* const* d_in, const int* in_sizes, int n_in,
                              void* d_out, int out_size, void* d_ws, size_t ws_size,
                              hipStream_t stream) {
    const float* x = (const float*)d_in[0];
    const float* v = (const float*)d_in[1];
    const int*   k = (const int*)  d_in[2];
    const float* X = (const float*)d_in[3];
    float* out = (float*)d_out;
    const int n = in_sizes[0] / GDIM;  // 16384 rows, 4 rows (waves) per block
    nc_kernel<<<n / 4, 256, 0, stream>>>(x, v, k, X, out);
}